// Round 8
// baseline (459.348 us; speedup 1.0000x reference)
//
#include <hip/hip_runtime.h>
#include <math.h>

#define MID 512
#define KT  16
#define NB  65536
#define G   4096
#define PTS 4128   // 258 blocks * 16 points; table point p holds x = (p-1)/G

struct NetP { const float *w1,*b1,*w2,*b2,*w3,*b3; };
struct AllP { NetP n[3]; float* table; };

// ---------------------------------------------------------------------------
// Kernel 0: transpose W2 (512x512) -> W2T[k][n] per net, so the k_siren slab
// (16 rows of W2T) is one CONTIGUOUS 8192-float block.
// ---------------------------------------------------------------------------
__global__ __launch_bounds__(256)
void k_prep(AllP P, float* __restrict__ w2t)
{
    __shared__ float t[32][33];
    const int net = blockIdx.z;
    const float* src = (net == 0) ? P.n[0].w2 : (net == 1) ? P.n[1].w2 : P.n[2].w2;
    float* dst = w2t + (size_t)net * MID * MID;
    const int bx = blockIdx.x * 32, by = blockIdx.y * 32;
    const int tx = threadIdx.x & 31, ty = threadIdx.x >> 5;   // ty 0..7
    #pragma unroll
    for (int j = 0; j < 4; ++j)
        t[ty + 8 * j][tx] = src[(size_t)(by + ty + 8 * j) * MID + bx + tx];
    __syncthreads();
    #pragma unroll
    for (int j = 0; j < 4; ++j)
        dst[(size_t)(bx + ty + 8 * j) * MID + by + tx] = t[tx][ty + 8 * j];
}

// ---------------------------------------------------------------------------
// Kernel 1: fused SIREN at 16 grid points/block, 256 threads (4 waves),
// 258 x 3 = 774 blocks (3.02 blocks/CU). Thread (pg=tid>>6, c=tid&63):
// points pg*4..pg*4+3, cols {c*4, 256+c*4}. Staging is a FLAT contiguous
// copy (coalesced global b128 + 16B/lane contiguous LDS writes -> 0 conflicts;
// round-7's sch*16 write pattern was an 8-way conflict = 1.9e7 counter).
// acc = 8 named float4. Layer 3 single-pass: full 32KB h2 in smemA, XOR swizzle.
// ---------------------------------------------------------------------------
__global__ __attribute__((amdgpu_waves_per_eu(2, 8))) __launch_bounds__(256)
void k_siren(AllP P, const float* __restrict__ w2t)
{
    __shared__ float smemA[KT * MID];   // 32 KB: W2T slab [kt][n] / layer3 h2
    __shared__ float hlds[KT * 16];     // 1 KB: h1 slab [kt][m]
    __shared__ float xs[16];

    const int tid = threadIdx.x;
    const int net = blockIdx.y;
    const int m0  = blockIdx.x * 16;
    NetP np;
    if (net == 0)      np = P.n[0];
    else if (net == 1) np = P.n[1];
    else               np = P.n[2];
    const float* wslab = w2t + (size_t)net * MID * MID;

    if (tid < 16) xs[tid] = ((float)(m0 + tid) - 1.0f) * (1.0f / (float)G);
    __syncthreads();

    const int c  = tid & 63;
    const int pg = tid >> 6;    // wave id 0..3 -> points pg*4 .. pg*4+3

#define ACC_DECL(i) float4 a##i##lo = make_float4(0.f,0.f,0.f,0.f); \
                    float4 a##i##hi = make_float4(0.f,0.f,0.f,0.f);
    ACC_DECL(0) ACC_DECL(1) ACC_DECL(2) ACC_DECL(3)

#define FMA8(i, hv) \
        a##i##lo.x = fmaf(hv, wa.x, a##i##lo.x); a##i##lo.y = fmaf(hv, wa.y, a##i##lo.y); \
        a##i##lo.z = fmaf(hv, wa.z, a##i##lo.z); a##i##lo.w = fmaf(hv, wa.w, a##i##lo.w); \
        a##i##hi.x = fmaf(hv, wb.x, a##i##hi.x); a##i##hi.y = fmaf(hv, wb.y, a##i##hi.y); \
        a##i##hi.z = fmaf(hv, wb.z, a##i##hi.z); a##i##hi.w = fmaf(hv, wb.w, a##i##hi.w);

    for (int ks = 0; ks < MID / KT; ++ks) {
        const int k0 = ks * KT;

        {   // h1 slab: 256 entries, one per thread
            const int kt = tid >> 4, m = tid & 15;
            const float zz = 4.f * fmaf(xs[m], np.w1[k0 + kt], np.b1[k0 + kt]);
            hlds[kt * 16 + m] = sinf(sinf(zz));
        }
        {   // W2T slab: flat contiguous copy of 8192 floats (2048 float4s)
            const float* src = wslab + (size_t)k0 * MID;
            #pragma unroll
            for (int q = 0; q < 8; ++q) {
                const int idx4 = q * 256 + tid;
                *reinterpret_cast<float4*>(&smemA[idx4 * 4]) =
                    *reinterpret_cast<const float4*>(src + idx4 * 4);
            }
        }
        __syncthreads();

        #pragma unroll
        for (int kt = 0; kt < KT; ++kt) {
            const float4 h  = *reinterpret_cast<const float4*>(&hlds[kt * 16 + pg * 4]);
            const float4 wa = *reinterpret_cast<const float4*>(&smemA[kt * MID + c * 4]);
            const float4 wb = *reinterpret_cast<const float4*>(&smemA[kt * MID + 256 + c * 4]);
            FMA8(0, h.x) FMA8(1, h.y) FMA8(2, h.z) FMA8(3, h.w)
        }
        __syncthreads();
    }

    {   // epilogue: h2 = sin(sin(4*(z + b2)))
        const float4 ba = *reinterpret_cast<const float4*>(np.b2 + c * 4);
        const float4 bb = *reinterpret_cast<const float4*>(np.b2 + 256 + c * 4);
#define SS1(v, b) v = sinf(sinf(4.f * ((v) + (b))));
#define SSROW(i) \
        SS1(a##i##lo.x, ba.x) SS1(a##i##lo.y, ba.y) SS1(a##i##lo.z, ba.z) SS1(a##i##lo.w, ba.w) \
        SS1(a##i##hi.x, bb.x) SS1(a##i##hi.y, bb.y) SS1(a##i##hi.z, bb.z) SS1(a##i##hi.w, bb.w)
        SSROW(0) SSROW(1) SSROW(2) SSROW(3)
    }

    // layer 3: single pass — full h2 (16 pts x 512 = 32KB) in smemA,
    // XOR-swizzled: phys float4 (row, n4) = row*128 + (n4 ^ row).
    // Store: per-instr row uniform, n4 per-lane permutation -> conflict-free.
    // Read: 16 rows same col-quad -> XOR spreads to 8 bank-groups x2 = free.
#define L3ST(i, sfx, nb) { const int rw = pg * 4 + i; \
    *reinterpret_cast<float4*>(&smemA[rw * 512 + (((nb) ^ rw) & 127) * 4]) = a##i##sfx; }
    L3ST(0, lo, c) L3ST(1, lo, c) L3ST(2, lo, c) L3ST(3, lo, c)
    L3ST(0, hi, 64 + c) L3ST(1, hi, 64 + c) L3ST(2, hi, 64 + c) L3ST(3, hi, 64 + c)
    __syncthreads();

    {
        const int m  = tid & 15;    // point
        const int jg = tid >> 4;    // 0..15 -> output cols jg*2, jg*2+1
        const float* wr0 = np.w3 + (size_t)(jg * 2) * MID;
        const float* wr1 = wr0 + MID;
        float p0a = 0.f, p0b = 0.f, p1a = 0.f, p1b = 0.f;
        #pragma unroll 8
        for (int qq = 0; qq < 128; ++qq) {
            const float4 h  = *reinterpret_cast<const float4*>(
                &smemA[m * 512 + ((qq ^ m) & 127) * 4]);
            const float4 w0 = *reinterpret_cast<const float4*>(wr0 + qq * 4);
            const float4 w1 = *reinterpret_cast<const float4*>(wr1 + qq * 4);
            p0a = fmaf(h.y, w0.y, fmaf(h.x, w0.x, p0a));
            p0b = fmaf(h.w, w0.w, fmaf(h.z, w0.z, p0b));
            p1a = fmaf(h.y, w1.y, fmaf(h.x, w1.x, p1a));
            p1b = fmaf(h.w, w1.w, fmaf(h.z, w1.z, p1b));
        }
        const float2 b3v = *reinterpret_cast<const float2*>(np.b3 + jg * 2);
        float2 r; r.x = p0a + p0b + b3v.x; r.y = p1a + p1b + b3v.y;
        *reinterpret_cast<float2*>(
            &P.table[((size_t)net * PTS + (m0 + m)) * 32 + jg * 2]) = r;
    }
}

// ---------------------------------------------------------------------------
// Kernel 2: Catmull-Rom interp + Tucker contraction, 2 SAMPLES PER THREAD
// (each broadcast C-read feeds 2 FMA chains -> LDS issue per FMA halved).
// 4 threads/sample-pair (rh wave-uniform), 128 samples/block, 512 blocks.
// waves_per_eu(2,2): ~170 VGPR live (W/X/V/Y = 128) — pin 256-VGPR budget.
// ---------------------------------------------------------------------------
#define F4MA(acc, s, rp, k) { const float4 _v = (rp)[k]; \
    acc.x = fmaf((s), _v.x, acc.x); acc.y = fmaf((s), _v.y, acc.y); \
    acc.z = fmaf((s), _v.z, acc.z); acc.w = fmaf((s), _v.w, acc.w); }

#define GROW8(Pfx, w, rp, off) \
    F4MA(Pfx##0,(w),rp,(off)+0) F4MA(Pfx##1,(w),rp,(off)+1) \
    F4MA(Pfx##2,(w),rp,(off)+2) F4MA(Pfx##3,(w),rp,(off)+3) \
    F4MA(Pfx##4,(w),rp,(off)+4) F4MA(Pfx##5,(w),rp,(off)+5) \
    F4MA(Pfx##6,(w),rp,(off)+6) F4MA(Pfx##7,(w),rp,(off)+7)

// Catmull-Rom setup: x*G is EXACT in fp32 (power-of-two scale).
#define CRSETUP(x_, iv, c0, c1, c2, c3) \
    int iv; float c0, c1, c2, c3; { \
        float xx = (x_) * (float)G; \
        int i = (int)xx; i = i < 0 ? 0 : (i > G - 1 ? G - 1 : i); iv = i; \
        float t = xx - (float)i; \
        float t2 = t * t, t3 = t2 * t; \
        c0 = fmaf(-0.5f, t3, t2) - 0.5f * t; \
        c1 = fmaf(1.5f, t3, fmaf(-2.5f, t2, 1.f)); \
        c2 = fmaf(-1.5f, t3, fmaf(2.f, t2, 0.5f * t)); \
        c3 = 0.5f * (t3 - t2); }

__global__ __attribute__((amdgpu_waves_per_eu(2, 2))) __launch_bounds__(256)
void k_ic(const float* __restrict__ table, const float* __restrict__ core,
          const float* __restrict__ x, float* __restrict__ out)
{
    __shared__ float cs[8 * 1024];   // 32 KB: 8 r-rows of C per round
    __shared__ float red[256];

    const int tid = threadIdx.x;
    const int ls  = tid & 63;        // local sample (first of pair)
    const int rh  = tid >> 6;        // 0..3, wave-uniform; r = rb*8+rh*2+{0,1}
    const int g0  = blockIdx.x * 128 + ls;
    const int g1  = g0 + 64;

    const float xu0 = x[(size_t)g0 * 3 + 0], xu1 = x[(size_t)g1 * 3 + 0];
    const float xv0 = x[(size_t)g0 * 3 + 1], xv1 = x[(size_t)g1 * 3 + 1];
    const float xw0 = x[(size_t)g0 * 3 + 2], xw1 = x[(size_t)g1 * 3 + 2];

#define DECLZ(Pn) float4 Pn = make_float4(0.f,0.f,0.f,0.f);
    DECLZ(W0) DECLZ(W1) DECLZ(W2) DECLZ(W3) DECLZ(W4) DECLZ(W5) DECLZ(W6) DECLZ(W7)
    DECLZ(X0) DECLZ(X1) DECLZ(X2) DECLZ(X3) DECLZ(X4) DECLZ(X5) DECLZ(X6) DECLZ(X7)
    DECLZ(V0) DECLZ(V1) DECLZ(V2) DECLZ(V3) DECLZ(V4) DECLZ(V5) DECLZ(V6) DECLZ(V7)
    DECLZ(Y0) DECLZ(Y1) DECLZ(Y2) DECLZ(Y3) DECLZ(Y4) DECLZ(Y5) DECLZ(Y6) DECLZ(Y7)
    float2 U0, U1, U2, U3, T0, T1, T2, T3;

    {   // W net (index 2), both samples
        CRSETUP(xw0, iw0, c0, c1, c2, c3)
        const float4* rp = reinterpret_cast<const float4*>(
            table + ((size_t)2 * PTS + iw0) * 32);
        GROW8(W, c0, rp, 0) GROW8(W, c1, rp, 8) GROW8(W, c2, rp, 16) GROW8(W, c3, rp, 24)
        CRSETUP(xw1, iw1, d0, d1, d2, d3)
        const float4* rq = reinterpret_cast<const float4*>(
            table + ((size_t)2 * PTS + iw1) * 32);
        GROW8(X, d0, rq, 0) GROW8(X, d1, rq, 8) GROW8(X, d2, rq, 16) GROW8(X, d3, rq, 24)
    }
    {   // V net (index 1), both samples
        CRSETUP(xv0, iv0, c0, c1, c2, c3)
        const float4* rp = reinterpret_cast<const float4*>(
            table + ((size_t)1 * PTS + iv0) * 32);
        GROW8(V, c0, rp, 0) GROW8(V, c1, rp, 8) GROW8(V, c2, rp, 16) GROW8(V, c3, rp, 24)
        CRSETUP(xv1, iv1, d0, d1, d2, d3)
        const float4* rq = reinterpret_cast<const float4*>(
            table + ((size_t)1 * PTS + iv1) * 32);
        GROW8(Y, d0, rq, 0) GROW8(Y, d1, rq, 8) GROW8(Y, d2, rq, 16) GROW8(Y, d3, rq, 24)
    }
    {   // U net (index 0): this thread's 8 r-cols = rb*8 + rh*2 + {0,1}
        CRSETUP(xu0, iu0, c0, c1, c2, c3)
        const float2* up = reinterpret_cast<const float2*>(table + (size_t)iu0 * 32);
#define UROW(rbv, dst, e0, e1, e2, e3, pp) { \
        const float2 t0 = pp[0 * 16 + (rbv) * 4 + rh]; \
        const float2 t1 = pp[1 * 16 + (rbv) * 4 + rh]; \
        const float2 t2 = pp[2 * 16 + (rbv) * 4 + rh]; \
        const float2 t3 = pp[3 * 16 + (rbv) * 4 + rh]; \
        dst.x = fmaf(e0,t0.x,fmaf(e1,t1.x,fmaf(e2,t2.x,e3*t3.x))); \
        dst.y = fmaf(e0,t0.y,fmaf(e1,t1.y,fmaf(e2,t2.y,e3*t3.y))); }
        UROW(0, U0, c0, c1, c2, c3, up) UROW(1, U1, c0, c1, c2, c3, up)
        UROW(2, U2, c0, c1, c2, c3, up) UROW(3, U3, c0, c1, c2, c3, up)
        CRSETUP(xu1, iu1, d0, d1, d2, d3)
        const float2* uq = reinterpret_cast<const float2*>(table + (size_t)iu1 * 32);
        UROW(0, T0, d0, d1, d2, d3, uq) UROW(1, T1, d0, d1, d2, d3, uq)
        UROW(2, T2, d0, d1, d2, d3, uq) UROW(3, T3, d0, d1, d2, d3, uq)
    }

#define TQ3(rl, s, tq, Wv, Xv, aa, bb) { \
    const float4 c4 = *reinterpret_cast<const float4*>( \
        &cs[(rh * 2 + (rl)) * 1024 + (s) * 32 + (tq) * 4]); \
    aa = fmaf(Wv.w, c4.w, fmaf(Wv.z, c4.z, fmaf(Wv.y, c4.y, fmaf(Wv.x, c4.x, aa)))); \
    bb = fmaf(Xv.w, c4.w, fmaf(Xv.z, c4.z, fmaf(Xv.y, c4.y, fmaf(Xv.x, c4.x, bb)))); }

#define SONE2(rl, s, vc0, vc1) { \
    float aA=0.f,aB=0.f,aC=0.f,aD=0.f,bA=0.f,bB=0.f,bC=0.f,bD=0.f; \
    TQ3(rl, s, 0, W0, X0, aA, bA) TQ3(rl, s, 1, W1, X1, aB, bB) \
    TQ3(rl, s, 2, W2, X2, aC, bC) TQ3(rl, s, 3, W3, X3, aD, bD) \
    TQ3(rl, s, 4, W4, X4, aA, bA) TQ3(rl, s, 5, W5, X5, aB, bB) \
    TQ3(rl, s, 6, W6, X6, aC, bC) TQ3(rl, s, 7, W7, X7, aD, bD) \
    tr0 = fmaf(vc0, (aA + aB) + (aC + aD), tr0); \
    tr1 = fmaf(vc1, (bA + bB) + (bC + bD), tr1); }

#define SG2(rl, sb, Vv, Yv) \
    SONE2(rl, 4*(sb)+0, Vv.x, Yv.x) SONE2(rl, 4*(sb)+1, Vv.y, Yv.y) \
    SONE2(rl, 4*(sb)+2, Vv.z, Yv.z) SONE2(rl, 4*(sb)+3, Vv.w, Yv.w)

#define RL2(rl, uc0, uc1) { float tr0 = 0.f, tr1 = 0.f; \
    SG2(rl, 0, V0, Y0) SG2(rl, 1, V1, Y1) SG2(rl, 2, V2, Y2) SG2(rl, 3, V3, Y3) \
    SG2(rl, 4, V4, Y4) SG2(rl, 5, V5, Y5) SG2(rl, 6, V6, Y6) SG2(rl, 7, V7, Y7) \
    o0 = fmaf(uc0, tr0, o0); o1 = fmaf(uc1, tr1, o1); }

#define RBLOCK2(rb) { \
    __syncthreads(); \
    _Pragma("unroll") \
    for (int cc = 0; cc < 8; ++cc) \
        *reinterpret_cast<float4*>(&cs[cc * 1024 + tid * 4]) = \
            *reinterpret_cast<const float4*>(core + (size_t)((rb) * 8 + cc) * 1024 + tid * 4); \
    __syncthreads(); \
    RL2(0, U##rb.x, T##rb.x) RL2(1, U##rb.y, T##rb.y) }

    float o0 = 0.f, o1 = 0.f;
    RBLOCK2(0) RBLOCK2(1) RBLOCK2(2) RBLOCK2(3)

    red[tid] = o0;
    __syncthreads();
    if (tid < 64)
        out[blockIdx.x * 128 + tid] =
            red[tid] + red[tid + 64] + red[tid + 128] + red[tid + 192];
    __syncthreads();
    red[tid] = o1;
    __syncthreads();
    if (tid < 64)
        out[blockIdx.x * 128 + 64 + tid] =
            red[tid] + red[tid + 64] + red[tid + 128] + red[tid + 192];
}

// ---------------------------------------------------------------------------
extern "C" void kernel_launch(void* const* d_in, const int* in_sizes, int n_in,
                              void* d_out, int out_size, void* d_ws, size_t ws_size,
                              hipStream_t stream)
{
    AllP P;
    for (int net = 0; net < 3; ++net) {
        const int b = 1 + net * 6;
        P.n[net].w1 = (const float*)d_in[b + 0];
        P.n[net].b1 = (const float*)d_in[b + 1];
        P.n[net].w2 = (const float*)d_in[b + 2];
        P.n[net].b2 = (const float*)d_in[b + 3];
        P.n[net].w3 = (const float*)d_in[b + 4];
        P.n[net].b3 = (const float*)d_in[b + 5];
    }
    const float* xin  = (const float*)d_in[0];
    const float* core = (const float*)d_in[19];
    float* wsf   = (float*)d_ws;
    float* table = wsf;                          // 3*4128*32 floats = 1.58 MB
    float* w2t   = wsf + (size_t)3 * PTS * 32;   // 3*512*512 floats = 3.0 MB
    P.table = table;

    k_prep <<<dim3(16, 16, 3), 256, 0, stream>>>(P, w2t);
    k_siren<<<dim3(PTS / 16, 3), 256, 0, stream>>>(P, w2t);
    k_ic   <<<NB / 128, 256, 0, stream>>>(table, core, xin, (float*)d_out);
}

// Round 9
// 297.033 us; speedup vs baseline: 1.5465x; 1.5465x over previous
//
#include <hip/hip_runtime.h>
#include <math.h>

#define MID 512
#define KT  16
#define NB  65536
#define G   4096
#define PTS 4128   // 258 blocks * 16 points; table point p holds x = (p-1)/G

struct NetP { const float *w1,*b1,*w2,*b2,*w3,*b3; };
struct AllP { NetP n[3]; float* table; };

// ---------------------------------------------------------------------------
// Kernel 0: transpose W2 (512x512) -> W2T[k][n] per net, so the k_siren slab
// (16 rows of W2T) is one CONTIGUOUS 8192-float block.
// ---------------------------------------------------------------------------
__global__ __launch_bounds__(256)
void k_prep(AllP P, float* __restrict__ w2t)
{
    __shared__ float t[32][33];
    const int net = blockIdx.z;
    const float* src = (net == 0) ? P.n[0].w2 : (net == 1) ? P.n[1].w2 : P.n[2].w2;
    float* dst = w2t + (size_t)net * MID * MID;
    const int bx = blockIdx.x * 32, by = blockIdx.y * 32;
    const int tx = threadIdx.x & 31, ty = threadIdx.x >> 5;   // ty 0..7
    #pragma unroll
    for (int j = 0; j < 4; ++j)
        t[ty + 8 * j][tx] = src[(size_t)(by + ty + 8 * j) * MID + bx + tx];
    __syncthreads();
    #pragma unroll
    for (int j = 0; j < 4; ++j)
        dst[(size_t)(bx + ty + 8 * j) * MID + by + tx] = t[tx][ty + 8 * j];
}

// ---------------------------------------------------------------------------
// Kernel 1: fused SIREN at 16 grid points/block, 256 threads (4 waves),
// 774 blocks. K-loop uses REGISTER PREFETCH (T14 issue-early/write-late):
// loads for slab ks+1 are issued right after the staging barrier and consumed
// at the next loop top, so L2 latency (~300-500cy) hides under the 1024-cycle
// FMA phase. Round-8 version drained vmcnt(0) serially between barriers ->
// VALUBusy 34%, all waves co-stalled.
// ---------------------------------------------------------------------------
__global__ __attribute__((amdgpu_waves_per_eu(2, 8))) __launch_bounds__(256)
void k_siren(AllP P, const float* __restrict__ w2t)
{
    __shared__ float smemA[KT * MID];   // 32 KB: W2T slab [kt][n] / layer3 h2
    __shared__ float hlds[KT * 16];     // 1 KB: h1 slab [kt][m]
    __shared__ float xs[16];

    const int tid = threadIdx.x;
    const int net = blockIdx.y;
    const int m0  = blockIdx.x * 16;
    NetP np;
    if (net == 0)      np = P.n[0];
    else if (net == 1) np = P.n[1];
    else               np = P.n[2];
    const float* wslab = w2t + (size_t)net * MID * MID;

    if (tid < 16) xs[tid] = ((float)(m0 + tid) - 1.0f) * (1.0f / (float)G);
    __syncthreads();

    const int c  = tid & 63;
    const int pg = tid >> 6;    // wave id 0..3 -> points pg*4 .. pg*4+3

#define ACC_DECL(i) float4 a##i##lo = make_float4(0.f,0.f,0.f,0.f); \
                    float4 a##i##hi = make_float4(0.f,0.f,0.f,0.f);
    ACC_DECL(0) ACC_DECL(1) ACC_DECL(2) ACC_DECL(3)

#define FMA8(i, hv) \
        a##i##lo.x = fmaf(hv, wa.x, a##i##lo.x); a##i##lo.y = fmaf(hv, wa.y, a##i##lo.y); \
        a##i##lo.z = fmaf(hv, wa.z, a##i##lo.z); a##i##lo.w = fmaf(hv, wa.w, a##i##lo.w); \
        a##i##hi.x = fmaf(hv, wb.x, a##i##hi.x); a##i##hi.y = fmaf(hv, wb.y, a##i##hi.y); \
        a##i##hi.z = fmaf(hv, wb.z, a##i##hi.z); a##i##hi.w = fmaf(hv, wb.w, a##i##hi.w);

    // prefetch registers: slab float4 #(q*256 + tid), q = 0..7
    float4 r0, r1, r2, r3, r4, r5, r6, r7;
    {
        const float* s0 = wslab + tid * 4;
        r0 = *reinterpret_cast<const float4*>(s0 + 0 * 1024);
        r1 = *reinterpret_cast<const float4*>(s0 + 1 * 1024);
        r2 = *reinterpret_cast<const float4*>(s0 + 2 * 1024);
        r3 = *reinterpret_cast<const float4*>(s0 + 3 * 1024);
        r4 = *reinterpret_cast<const float4*>(s0 + 4 * 1024);
        r5 = *reinterpret_cast<const float4*>(s0 + 5 * 1024);
        r6 = *reinterpret_cast<const float4*>(s0 + 6 * 1024);
        r7 = *reinterpret_cast<const float4*>(s0 + 7 * 1024);
    }

    for (int ks = 0; ks < MID / KT; ++ks) {
        const int k0 = ks * KT;

        __syncthreads();   // (A) all waves done READING previous slab
        {   // write slab ks from prefetch regs (16B/lane contiguous, 0-conflict)
            float* d0 = &smemA[tid * 4];
            *reinterpret_cast<float4*>(d0 + 0 * 1024) = r0;
            *reinterpret_cast<float4*>(d0 + 1 * 1024) = r1;
            *reinterpret_cast<float4*>(d0 + 2 * 1024) = r2;
            *reinterpret_cast<float4*>(d0 + 3 * 1024) = r3;
            *reinterpret_cast<float4*>(d0 + 4 * 1024) = r4;
            *reinterpret_cast<float4*>(d0 + 5 * 1024) = r5;
            *reinterpret_cast<float4*>(d0 + 6 * 1024) = r6;
            *reinterpret_cast<float4*>(d0 + 7 * 1024) = r7;
        }
        {   // h1 slab: 256 entries, one per thread
            const int kt = tid >> 4, m = tid & 15;
            const float zz = 4.f * fmaf(xs[m], np.w1[k0 + kt], np.b1[k0 + kt]);
            hlds[kt * 16 + m] = sinf(sinf(zz));
        }
        __syncthreads();   // (B) slab ks visible

        if (ks + 1 < MID / KT) {   // issue loads for slab ks+1 (consumed at next (A))
            const float* s1 = wslab + (size_t)(ks + 1) * KT * MID + tid * 4;
            r0 = *reinterpret_cast<const float4*>(s1 + 0 * 1024);
            r1 = *reinterpret_cast<const float4*>(s1 + 1 * 1024);
            r2 = *reinterpret_cast<const float4*>(s1 + 2 * 1024);
            r3 = *reinterpret_cast<const float4*>(s1 + 3 * 1024);
            r4 = *reinterpret_cast<const float4*>(s1 + 4 * 1024);
            r5 = *reinterpret_cast<const float4*>(s1 + 5 * 1024);
            r6 = *reinterpret_cast<const float4*>(s1 + 6 * 1024);
            r7 = *reinterpret_cast<const float4*>(s1 + 7 * 1024);
        }

        #pragma unroll
        for (int kt = 0; kt < KT; ++kt) {
            const float4 h  = *reinterpret_cast<const float4*>(&hlds[kt * 16 + pg * 4]);
            const float4 wa = *reinterpret_cast<const float4*>(&smemA[kt * MID + c * 4]);
            const float4 wb = *reinterpret_cast<const float4*>(&smemA[kt * MID + 256 + c * 4]);
            FMA8(0, h.x) FMA8(1, h.y) FMA8(2, h.z) FMA8(3, h.w)
        }
    }
    __syncthreads();

    {   // epilogue: h2 = sin(sin(4*(z + b2)))
        const float4 ba = *reinterpret_cast<const float4*>(np.b2 + c * 4);
        const float4 bb = *reinterpret_cast<const float4*>(np.b2 + 256 + c * 4);
#define SS1(v, b) v = sinf(sinf(4.f * ((v) + (b))));
#define SSROW(i) \
        SS1(a##i##lo.x, ba.x) SS1(a##i##lo.y, ba.y) SS1(a##i##lo.z, ba.z) SS1(a##i##lo.w, ba.w) \
        SS1(a##i##hi.x, bb.x) SS1(a##i##hi.y, bb.y) SS1(a##i##hi.z, bb.z) SS1(a##i##hi.w, bb.w)
        SSROW(0) SSROW(1) SSROW(2) SSROW(3)
    }

    // layer 3: single pass — full h2 (16 pts x 512 = 32KB) in smemA,
    // XOR-swizzled: phys float4 (row, n4) = row*128 + (n4 ^ row).
#define L3ST(i, sfx, nb) { const int rw = pg * 4 + i; \
    *reinterpret_cast<float4*>(&smemA[rw * 512 + (((nb) ^ rw) & 127) * 4]) = a##i##sfx; }
    L3ST(0, lo, c) L3ST(1, lo, c) L3ST(2, lo, c) L3ST(3, lo, c)
    L3ST(0, hi, 64 + c) L3ST(1, hi, 64 + c) L3ST(2, hi, 64 + c) L3ST(3, hi, 64 + c)
    __syncthreads();

    {
        const int m  = tid & 15;    // point
        const int jg = tid >> 4;    // 0..15 -> output cols jg*2, jg*2+1
        const float* wr0 = np.w3 + (size_t)(jg * 2) * MID;
        const float* wr1 = wr0 + MID;
        float p0a = 0.f, p0b = 0.f, p1a = 0.f, p1b = 0.f;
        #pragma unroll 8
        for (int qq = 0; qq < 128; ++qq) {
            const float4 h  = *reinterpret_cast<const float4*>(
                &smemA[m * 512 + ((qq ^ m) & 127) * 4]);
            const float4 w0 = *reinterpret_cast<const float4*>(wr0 + qq * 4);
            const float4 w1 = *reinterpret_cast<const float4*>(wr1 + qq * 4);
            p0a = fmaf(h.y, w0.y, fmaf(h.x, w0.x, p0a));
            p0b = fmaf(h.w, w0.w, fmaf(h.z, w0.z, p0b));
            p1a = fmaf(h.y, w1.y, fmaf(h.x, w1.x, p1a));
            p1b = fmaf(h.w, w1.w, fmaf(h.z, w1.z, p1b));
        }
        const float2 b3v = *reinterpret_cast<const float2*>(np.b3 + jg * 2);
        float2 r; r.x = p0a + p0b + b3v.x; r.y = p1a + p1b + b3v.y;
        *reinterpret_cast<float2*>(
            &P.table[((size_t)net * PTS + (m0 + m)) * 32 + jg * 2]) = r;
    }
}

// ---------------------------------------------------------------------------
// Kernel 2: Catmull-Rom interp + Tucker contraction — ROUND-6 VERSION VERBATIM
// (measured ~93 us; rounds 7-8 "ILP improvements" regressed it to ~150/~200).
// 4 threads/sample (rh wave-uniform -> core LDS reads are broadcasts),
// 64 samples/block, 1024 blocks.
// ---------------------------------------------------------------------------
#define F4MA(acc, s, rp, k) { const float4 _v = (rp)[k]; \
    acc.x = fmaf((s), _v.x, acc.x); acc.y = fmaf((s), _v.y, acc.y); \
    acc.z = fmaf((s), _v.z, acc.z); acc.w = fmaf((s), _v.w, acc.w); }

#define GROW8(Pfx, w, rp, off) \
    F4MA(Pfx##0,(w),rp,(off)+0) F4MA(Pfx##1,(w),rp,(off)+1) \
    F4MA(Pfx##2,(w),rp,(off)+2) F4MA(Pfx##3,(w),rp,(off)+3) \
    F4MA(Pfx##4,(w),rp,(off)+4) F4MA(Pfx##5,(w),rp,(off)+5) \
    F4MA(Pfx##6,(w),rp,(off)+6) F4MA(Pfx##7,(w),rp,(off)+7)

// Catmull-Rom setup: x*G is EXACT in fp32 (power-of-two scale).
#define CRSETUP(x_, iv, c0, c1, c2, c3) \
    int iv; float c0, c1, c2, c3; { \
        float xx = (x_) * (float)G; \
        int i = (int)xx; i = i < 0 ? 0 : (i > G - 1 ? G - 1 : i); iv = i; \
        float t = xx - (float)i; \
        float t2 = t * t, t3 = t2 * t; \
        c0 = fmaf(-0.5f, t3, t2) - 0.5f * t; \
        c1 = fmaf(1.5f, t3, fmaf(-2.5f, t2, 1.f)); \
        c2 = fmaf(-1.5f, t3, fmaf(2.f, t2, 0.5f * t)); \
        c3 = 0.5f * (t3 - t2); }

__global__ __attribute__((amdgpu_waves_per_eu(2, 4))) __launch_bounds__(256)
void k_ic(const float* __restrict__ table, const float* __restrict__ core,
          const float* __restrict__ x, float* __restrict__ out)
{
    __shared__ float cs[8 * 1024];   // 32 KB: 8 r-rows of C per round
    __shared__ float red[256];

    const int tid = threadIdx.x;
    const int ls  = tid & 63;        // local sample
    const int rh  = tid >> 6;        // 0..3, wave-uniform; r = rb*8+rh*2+{0,1}
    const int g   = blockIdx.x * 64 + ls;

    const float xu = x[(size_t)g * 3 + 0];
    const float xv = x[(size_t)g * 3 + 1];
    const float xw = x[(size_t)g * 3 + 2];

#define DECLZ(Pn) float4 Pn = make_float4(0.f,0.f,0.f,0.f);
    DECLZ(W0) DECLZ(W1) DECLZ(W2) DECLZ(W3) DECLZ(W4) DECLZ(W5) DECLZ(W6) DECLZ(W7)
    DECLZ(V0) DECLZ(V1) DECLZ(V2) DECLZ(V3) DECLZ(V4) DECLZ(V5) DECLZ(V6) DECLZ(V7)
    float2 U0, U1, U2, U3;

    {   // W net (index 2)
        CRSETUP(xw, iw, c0, c1, c2, c3)
        const float4* rp = reinterpret_cast<const float4*>(
            table + ((size_t)2 * PTS + iw) * 32);
        GROW8(W, c0, rp, 0) GROW8(W, c1, rp, 8) GROW8(W, c2, rp, 16) GROW8(W, c3, rp, 24)
    }
    {   // V net (index 1)
        CRSETUP(xv, iv2, c0, c1, c2, c3)
        const float4* rp = reinterpret_cast<const float4*>(
            table + ((size_t)1 * PTS + iv2) * 32);
        GROW8(V, c0, rp, 0) GROW8(V, c1, rp, 8) GROW8(V, c2, rp, 16) GROW8(V, c3, rp, 24)
    }
    {   // U net (index 0): this thread's 8 r-cols = rb*8 + rh*2 + {0,1}
        CRSETUP(xu, iu, c0, c1, c2, c3)
        const float2* up = reinterpret_cast<const float2*>(table + (size_t)iu * 32);
#define UROW(rbv, dst) { \
        const float2 t0 = up[0 * 16 + (rbv) * 4 + rh]; \
        const float2 t1 = up[1 * 16 + (rbv) * 4 + rh]; \
        const float2 t2 = up[2 * 16 + (rbv) * 4 + rh]; \
        const float2 t3 = up[3 * 16 + (rbv) * 4 + rh]; \
        dst.x = fmaf(c0,t0.x,fmaf(c1,t1.x,fmaf(c2,t2.x,c3*t3.x))); \
        dst.y = fmaf(c0,t0.y,fmaf(c1,t1.y,fmaf(c2,t2.y,c3*t3.y))); }
        UROW(0, U0) UROW(1, U1) UROW(2, U2) UROW(3, U3)
    }

#define TQC(rl, s, tq, Wv) { \
    const float4 c4 = *reinterpret_cast<const float4*>( \
        &cs[(rh * 2 + (rl)) * 1024 + (s) * 32 + (tq) * 4]); \
    aa = fmaf(Wv.w, c4.w, fmaf(Wv.z, c4.z, fmaf(Wv.y, c4.y, fmaf(Wv.x, c4.x, aa)))); }

#define SONE(rl, s, vcomp) { float aa = 0.f; \
    TQC(rl, s, 0, W0) TQC(rl, s, 1, W1) TQC(rl, s, 2, W2) TQC(rl, s, 3, W3) \
    TQC(rl, s, 4, W4) TQC(rl, s, 5, W5) TQC(rl, s, 6, W6) TQC(rl, s, 7, W7) \
    tracc = fmaf(vcomp, aa, tracc); }

#define SG(rl, sb, Vv) \
    SONE(rl, 4*(sb)+0, Vv.x) SONE(rl, 4*(sb)+1, Vv.y) \
    SONE(rl, 4*(sb)+2, Vv.z) SONE(rl, 4*(sb)+3, Vv.w)

#define RL1(rl, ucomp) { float tracc = 0.f; \
    SG(rl, 0, V0) SG(rl, 1, V1) SG(rl, 2, V2) SG(rl, 3, V3) \
    SG(rl, 4, V4) SG(rl, 5, V5) SG(rl, 6, V6) SG(rl, 7, V7) \
    o = fmaf(ucomp, tracc, o); }

#define RBLOCK(rb) { \
    __syncthreads(); \
    _Pragma("unroll") \
    for (int cc = 0; cc < 8; ++cc) \
        *reinterpret_cast<float4*>(&cs[cc * 1024 + tid * 4]) = \
            *reinterpret_cast<const float4*>(core + (size_t)((rb) * 8 + cc) * 1024 + tid * 4); \
    __syncthreads(); \
    RL1(0, U##rb.x) RL1(1, U##rb.y) }

    float o = 0.f;
    RBLOCK(0) RBLOCK(1) RBLOCK(2) RBLOCK(3)

    red[tid] = o;
    __syncthreads();
    if (tid < 64)
        out[blockIdx.x * 64 + tid] =
            red[tid] + red[tid + 64] + red[tid + 128] + red[tid + 192];
}

// ---------------------------------------------------------------------------
extern "C" void kernel_launch(void* const* d_in, const int* in_sizes, int n_in,
                              void* d_out, int out_size, void* d_ws, size_t ws_size,
                              hipStream_t stream)
{
    AllP P;
    for (int net = 0; net < 3; ++net) {
        const int b = 1 + net * 6;
        P.n[net].w1 = (const float*)d_in[b + 0];
        P.n[net].b1 = (const float*)d_in[b + 1];
        P.n[net].w2 = (const float*)d_in[b + 2];
        P.n[net].b2 = (const float*)d_in[b + 3];
        P.n[net].w3 = (const float*)d_in[b + 4];
        P.n[net].b3 = (const float*)d_in[b + 5];
    }
    const float* xin  = (const float*)d_in[0];
    const float* core = (const float*)d_in[19];
    float* wsf   = (float*)d_ws;
    float* table = wsf;                          // 3*4128*32 floats = 1.58 MB
    float* w2t   = wsf + (size_t)3 * PTS * 32;   // 3*512*512 floats = 3.0 MB
    P.table = table;

    k_prep <<<dim3(16, 16, 3), 256, 0, stream>>>(P, w2t);
    k_siren<<<dim3(PTS / 16, 3), 256, 0, stream>>>(P, w2t);
    k_ic   <<<NB / 64, 256, 0, stream>>>(table, core, xin, (float*)d_out);
}